// Round 2
// baseline (407.015 us; speedup 1.0000x reference)
//
#include <hip/hip_runtime.h>
#include <stdint.h>

typedef __attribute__((ext_vector_type(4))) int v4i;

#define BATCH 8192
#define KDIM  4096
#define NOUT  4096

// pack x: fp32 -> i8 {1,0}, 16 elems/thread, 16B stores
__global__ __launch_bounds__(256) void pack_x(const float* __restrict__ x,
                                              uint4* __restrict__ xb) {
    size_t t = (size_t)blockIdx.x * 256 + threadIdx.x;
    const float4* xp = (const float4*)x + t * 4;
    uint32_t o[4];
    #pragma unroll
    for (int i = 0; i < 4; ++i) {
        float4 f = xp[i];
        o[i] = (f.x > 0.f ? 1u : 0u)
             | ((f.y > 0.f ? 1u : 0u) << 8)
             | ((f.z > 0.f ? 1u : 0u) << 16)
             | ((f.w > 0.f ? 1u : 0u) << 24);
    }
    xb[t] = make_uint4(o[0], o[1], o[2], o[3]);
}

// pack W: fp32 -> i8 {+1,-1}, 16 elems/thread, 16B stores
__global__ __launch_bounds__(256) void pack_w(const float* __restrict__ w,
                                              uint4* __restrict__ wb) {
    size_t t = (size_t)blockIdx.x * 256 + threadIdx.x;
    const float4* wp = (const float4*)w + t * 4;
    uint32_t o[4];
    #pragma unroll
    for (int i = 0; i < 4; ++i) {
        float4 f = wp[i];
        o[i] = (f.x > 0.f ? 0x01u : 0xFFu)
             | ((f.y > 0.f ? 0x01u : 0xFFu) << 8)
             | ((f.z > 0.f ? 0x01u : 0xFFu) << 16)
             | ((f.w > 0.f ? 0x01u : 0xFFu) << 24);
    }
    wb[t] = make_uint4(o[0], o[1], o[2], o[3]);
}

// C[M,N] = A[M,K] * B[N,K]^T, i8 in, f32 out (integer-exact).
// 128x128 block tile, BK=128 (2 MFMA k-steps per barrier pair -> half the
// vmcnt(0) barrier drains of BK=64), 4 waves (2x2 of 64x64), width-16
// global_load_lds staging, 16x16x64 i8 MFMA, 4x4 acc tiles/wave.
// LDS rows are 128B (= exactly 32 banks); chunk c of row r stored at
// physical chunk c^(r&7) via the GLOBAL fetch address (global_load_lds
// forces lds dst = wave-uniform base + lane*16). Fragment reads then hit
// each 4-bank group with exactly 8 lanes = the b128 floor -> 0 conflicts
// (measured 0 in R1 with the 64B-row variant of this scheme).
__global__ __launch_bounds__(256) void bin_gemm(const int8_t* __restrict__ A,
                                                const int8_t* __restrict__ B,
                                                float* __restrict__ C) {
    __shared__ __align__(16) int8_t smA[128 * 128];
    __shared__ __align__(16) int8_t smB[128 * 128];

    const int tid  = threadIdx.x;
    const int w    = tid >> 6;          // wave 0..3
    const int lane = tid & 63;
    const int q    = lane >> 4;         // quad 0..3
    const int mp   = lane & 15;

    const int Mbase = blockIdx.y * 128;
    const int Nbase = blockIdx.x * 128;
    const int wm = (w >> 1) * 64;       // wave M offset in tile
    const int wn = (w & 1) * 64;        // wave N offset in tile

    // Staging: tile = 128 rows x 8 chunks(16B) = 1024 chunks; 256 threads
    // x 4 iters. idx = i*256 + tid; row = idx>>3; phys chunk = idx&7;
    // global chunk = phys ^ (row&7).
    const int8_t* gA[4];
    const int8_t* gB[4];
    #pragma unroll
    for (int i = 0; i < 4; ++i) {
        int idx = i * 256 + tid;
        int row = idx >> 3;
        int cg  = (idx & 7) ^ (row & 7);
        gA[i] = A + (size_t)(Mbase + row) * KDIM + cg * 16;
        gB[i] = B + (size_t)(Nbase + row) * KDIM + cg * 16;
    }

    // Fragment read slots: k-step s, quad q reads logical chunk s*4+q of
    // row (..+mp); physical = (s*4+q) ^ (mp&7).
    const int slot0 = ((0 + q) ^ (mp & 7)) * 16;
    const int slot1 = ((4 + q) ^ (mp & 7)) * 16;

    v4i acc[4][4] = {};

    for (int kt = 0; kt < KDIM / 128; ++kt) {
        const int kof = kt * 128;
        #pragma unroll
        for (int i = 0; i < 4; ++i) {
            __builtin_amdgcn_global_load_lds(
                (__attribute__((address_space(1))) void*)(gA[i] + kof),
                (__attribute__((address_space(3))) void*)(smA + (i * 256 + w * 64) * 16),
                16, 0, 0);
            __builtin_amdgcn_global_load_lds(
                (__attribute__((address_space(1))) void*)(gB[i] + kof),
                (__attribute__((address_space(3))) void*)(smB + (i * 256 + w * 64) * 16),
                16, 0, 0);
        }
        __syncthreads();

        // k-step 0
        {
            v4i af[4], bf[4];
            #pragma unroll
            for (int i = 0; i < 4; ++i)
                af[i] = *(const v4i*)(smA + (wm + i * 16 + mp) * 128 + slot0);
            #pragma unroll
            for (int i = 0; i < 4; ++i)
                bf[i] = *(const v4i*)(smB + (wn + i * 16 + mp) * 128 + slot0);
            #pragma unroll
            for (int mi = 0; mi < 4; ++mi)
                #pragma unroll
                for (int ni = 0; ni < 4; ++ni)
                    acc[mi][ni] = __builtin_amdgcn_mfma_i32_16x16x64_i8(
                        af[mi], bf[ni], acc[mi][ni], 0, 0, 0);
        }
        // k-step 1
        {
            v4i af[4], bf[4];
            #pragma unroll
            for (int i = 0; i < 4; ++i)
                af[i] = *(const v4i*)(smA + (wm + i * 16 + mp) * 128 + slot1);
            #pragma unroll
            for (int i = 0; i < 4; ++i)
                bf[i] = *(const v4i*)(smB + (wn + i * 16 + mp) * 128 + slot1);
            #pragma unroll
            for (int mi = 0; mi < 4; ++mi)
                #pragma unroll
                for (int ni = 0; ni < 4; ++ni)
                    acc[mi][ni] = __builtin_amdgcn_mfma_i32_16x16x64_i8(
                        af[mi], bf[ni], acc[mi][ni], 0, 0, 0);
        }
        __syncthreads();
    }

    // C/D layout: col = lane&15, row = quad*4 + reg (shape-determined).
    float* Cp = C + (size_t)(Mbase + wm + q * 4) * NOUT + (Nbase + wn + mp);
    #pragma unroll
    for (int mi = 0; mi < 4; ++mi)
        #pragma unroll
        for (int ni = 0; ni < 4; ++ni)
            #pragma unroll
            for (int r = 0; r < 4; ++r)
                Cp[(size_t)(mi * 16 + r) * NOUT + ni * 16] = (float)acc[mi][ni][r];
}

extern "C" void kernel_launch(void* const* d_in, const int* in_sizes, int n_in,
                              void* d_out, int out_size, void* d_ws, size_t ws_size,
                              hipStream_t stream) {
    const float* x = (const float*)d_in[0];   // [8192, 4096] f32
    const float* W = (const float*)d_in[1];   // [4096, 4096] f32, values +/-1
    float* out = (float*)d_out;               // [8192, 4096] f32

    int8_t* xb = (int8_t*)d_ws;                           // 32 MiB
    int8_t* wb = (int8_t*)d_ws + (size_t)BATCH * KDIM;    // 16 MiB (48 MiB ws total)

    pack_x<<<(BATCH * (size_t)KDIM / 16) / 256, 256, 0, stream>>>(x, (uint4*)xb);
    pack_w<<<((size_t)NOUT * KDIM / 16) / 256, 256, 0, stream>>>(W, (uint4*)wb);

    dim3 grid(NOUT / 128, BATCH / 128);   // (32, 64) = 2048 blocks
    bin_gemm<<<grid, 256, 0, stream>>>(xb, wb, out);
}